// Round 9
// baseline (80.729 us; speedup 1.0000x reference)
//
#include <hip/hip_runtime.h>

#define IN_F    512
#define NC      4096
#define OUT_COLS 640
#define B_SZ    128
#define KD      32

typedef __attribute__((ext_vector_type(8))) short  bf16x8;
typedef __attribute__((ext_vector_type(4))) float  f32x4;

static __device__ __forceinline__ unsigned short f2bfu(float f) {
    return (unsigned short)(__float_as_uint(f) >> 16);
}
static __device__ __forceinline__ unsigned int pack2(float lo, float hi) {
    return (__float_as_uint(lo) >> 16) | (__float_as_uint(hi) & 0xFFFF0000u);
}

// A-frag pack: xa[slot*8+e] = bf16(x[(mt*16+col)*512 + kt*32 + q*8 + e]),
// slot = (mt*16+kt)*64 + lane, lane = q*16+col. Also copies x -> out[:, :512].
__global__ __launch_bounds__(256) void prep_kernel(
    const float* __restrict__ x, float* __restrict__ out,
    unsigned short* __restrict__ xa)
{
    const int g = blockIdx.x * 256 + threadIdx.x;   // 0..16383
    // x -> out copy (float4 g covers all of x)
    {
        int b = g >> 7, c4 = g & 127;
        float4 v = ((const float4*)x)[g];
        *(float4*)(out + b * OUT_COLS + c4 * 4) = v;
    }
    // fragment pack: half-slot per thread
    const int s = g >> 1, half = g & 1;
    const int mt = s >> 10, kt = (s >> 6) & 15, lane = s & 63;
    const int col = lane & 15, q = lane >> 4;
    float4 v = *(const float4*)(x + (mt * 16 + col) * IN_F + kt * 32 + q * 8 + half * 4);
    uint2 pv; pv.x = pack2(v.x, v.y); pv.y = pack2(v.z, v.w);
    *(uint2*)(xa + (size_t)s * 8 + half * 4) = pv;
}

// B-frag pack: tb[slot*8+j] = bf16(T[(kt*32+q*8+j)*4096 + nt*16+col]),
// slot = (nt*16+kt)*64 + lane. T read once (8 MB), tb written once (4 MB).
__global__ __launch_bounds__(256) void prepT_kernel(
    const float* __restrict__ T, unsigned short* __restrict__ tb)
{
    const int s = blockIdx.x * 256 + threadIdx.x;   // 0..262143
    const int nt = s >> 10, kt = (s >> 6) & 15, lane = s & 63;
    const int col = lane & 15, q = lane >> 4;
    const float* src = T + (size_t)(kt * 32 + q * 8) * NC + nt * 16 + col;
    float b0 = src[0*NC], b1 = src[1*NC], b2 = src[2*NC], b3 = src[3*NC];
    float b4 = src[4*NC], b5 = src[5*NC], b6 = src[6*NC], b7 = src[7*NC];
    uint4 pv;
    pv.x = pack2(b0, b1); pv.y = pack2(b2, b3);
    pv.z = pack2(b4, b5); pv.w = pack2(b6, b7);
    *(uint4*)(tb + (size_t)s * 8) = pv;
}

// GEMM: no LDS, no barriers. Wave t = (nt, mt) does 16x16 tile, K=512:
// 16 x (two coalesced 1KB fragment loads + 1 MFMA). m stored [o][b][k].
__global__ __launch_bounds__(256) void gemm_kernel(
    const unsigned short* __restrict__ xa,
    const unsigned short* __restrict__ tb,
    float* __restrict__ m)                  // fp32 [128 o][128 b][32 k]
{
    const int tid  = threadIdx.x;
    const int lane = tid & 63;
    const int w    = tid >> 6;
    const int t    = blockIdx.x * 4 + w;    // 0..2047
    const int nt   = t >> 3, mt = t & 7;
    const int col  = lane & 15, q = lane >> 4;

    f32x4 acc = {0.f, 0.f, 0.f, 0.f};
    const unsigned short* pa = xa + (size_t)(mt * 16) * 512 + lane * 8;  // (mt*16+kt)*64*8
    const unsigned short* pb = tb + (size_t)(nt * 16) * 512 + lane * 8;
    #pragma unroll 8
    for (int kt = 0; kt < 16; ++kt) {
        bf16x8 af  = *(const bf16x8*)(pa + (size_t)kt * 512);
        bf16x8 bfr = *(const bf16x8*)(pb + (size_t)kt * 512);
        acc = __builtin_amdgcn_mfma_f32_16x16x32_bf16(af, bfr, acc, 0, 0, 0);
    }
    const int n = nt * 16 + col, o = n >> 5, nk = n & 31;
    float* dst = m + (size_t)o * (B_SZ * KD) + (mt * 16 + q * 4) * KD + nk;
    dst[0 * KD] = acc[0]; dst[1 * KD] = acc[1];
    dst[2 * KD] = acc[2]; dst[3 * KD] = acc[3];
}

// o_b[j][o] = sum_i exp(-L1(m_i, m_j)) - 1. R3-proven 512-thr shape + 2j/thread.
__global__ __launch_bounds__(512) void pairwise_kernel(
    const float* __restrict__ m,            // [o][b][k], strips contiguous
    float* __restrict__ out)
{
    __shared__ float mo[B_SZ * KD];         // 16 KB, flat [b][k]
    __shared__ float psum[2 * 32 * 17];

    const int tid   = threadIdx.x;
    const int o     = blockIdx.x >> 1;
    const int jhalf = blockIdx.x & 1;

    const float4* src = (const float4*)(m + (size_t)o * (B_SZ * KD));
    ((float4*)mo)[tid]       = src[tid];
    ((float4*)mo)[tid + 512] = src[tid + 512];
    __syncthreads();

    const int jj5 = tid & 31;               // j-slot
    const int isl = tid >> 5;               // i-slice 0..15
    const int j0  = jhalf * 64 + jj5;

    float mj0[KD], mj1[KD];
    #pragma unroll
    for (int k4 = 0; k4 < 8; ++k4) {        // one-time global strided loads
        float4 a = *(const float4*)(m + (size_t)o * (B_SZ * KD) + j0 * KD + k4 * 4);
        float4 b = *(const float4*)(m + (size_t)o * (B_SZ * KD) + (j0 + 32) * KD + k4 * 4);
        mj0[k4*4+0] = a.x; mj0[k4*4+1] = a.y; mj0[k4*4+2] = a.z; mj0[k4*4+3] = a.w;
        mj1[k4*4+0] = b.x; mj1[k4*4+1] = b.y; mj1[k4*4+2] = b.z; mj1[k4*4+3] = b.w;
    }

    float s0 = 0.f, s1 = 0.f;
    #pragma unroll
    for (int ii = 0; ii < 8; ++ii) {
        const int i = isl * 8 + ii;
        float n0 = 0.f, n1 = 0.f;
        #pragma unroll
        for (int k4 = 0; k4 < 8; ++k4) {
            float4 v = ((const float4*)mo)[i * 8 + k4];   // half-wave broadcast
            n0 += fabsf(mj0[k4*4+0] - v.x) + fabsf(mj0[k4*4+1] - v.y)
                + fabsf(mj0[k4*4+2] - v.z) + fabsf(mj0[k4*4+3] - v.w);
            n1 += fabsf(mj1[k4*4+0] - v.x) + fabsf(mj1[k4*4+1] - v.y)
                + fabsf(mj1[k4*4+2] - v.z) + fabsf(mj1[k4*4+3] - v.w);
        }
        s0 += __expf(-n0);
        s1 += __expf(-n1);
    }
    psum[jj5 * 17 + isl]       = s0;        // pitch 17: conflict-free
    psum[544 + jj5 * 17 + isl] = s1;
    __syncthreads();
    if (tid < 64) {
        int jsel = tid >> 5, jj = tid & 31;
        float tot = 0.f;
        #pragma unroll
        for (int u = 0; u < 16; ++u) tot += psum[jsel * 544 + jj * 17 + u];
        out[(jhalf * 64 + jsel * 32 + jj) * OUT_COLS + IN_F + o] = tot - 1.0f;
    }
}

extern "C" void kernel_launch(void* const* d_in, const int* in_sizes, int n_in,
                              void* d_out, int out_size, void* d_ws, size_t ws_size,
                              hipStream_t stream) {
    const float* x = (const float*)d_in[0];
    const float* T = (const float*)d_in[1];
    float* out = (float*)d_out;
    float* m = (float*)d_ws;                                            // 2 MB
    unsigned short* xa = (unsigned short*)((char*)d_ws + (2u << 20));   // 128 KB
    unsigned short* tb = (unsigned short*)((char*)d_ws + (2u << 20) + (128u << 10)); // 4 MB

    prep_kernel<<<64, 256, 0, stream>>>(x, out, xa);
    prepT_kernel<<<1024, 256, 0, stream>>>(T, tb);
    gemm_kernel<<<512, 256, 0, stream>>>(xa, tb, m);
    pairwise_kernel<<<256, 512, 0, stream>>>(m, out);
}

// Round 10
// 71.059 us; speedup vs baseline: 1.1361x; 1.1361x over previous
//
#include <hip/hip_runtime.h>

#define IN_F    512
#define NC      4096
#define OUT_COLS 640
#define B_SZ    128
#define KD      32
#define MO_PITCH 36

typedef __attribute__((ext_vector_type(8))) short  bf16x8;
typedef __attribute__((ext_vector_type(4))) float  f32x4;

static __device__ __forceinline__ unsigned short f2bfu(float f) {
    return (unsigned short)(__float_as_uint(f) >> 16);
}
static __device__ __forceinline__ unsigned int pack2(float lo, float hi) {
    return (__float_as_uint(lo) >> 16) | (__float_as_uint(hi) & 0xFFFF0000u);
}

// prep: x -> out[:, :512] copy + A-fragment pack (same layout R9 verified):
// xa[slot*8+e] = bf16(x[(mt*16+col)*512 + kt*32 + q*8 + e]), slot=(mt*16+kt)*64+lane
__global__ __launch_bounds__(256) void prep_kernel(
    const float* __restrict__ x, float* __restrict__ out,
    unsigned short* __restrict__ xa)
{
    const int g = blockIdx.x * 256 + threadIdx.x;   // 0..16383
    {
        int b = g >> 7, c4 = g & 127;
        float4 v = ((const float4*)x)[g];
        *(float4*)(out + b * OUT_COLS + c4 * 4) = v;
    }
    const int s = g >> 1, half = g & 1;
    const int mt = s >> 10, kt = (s >> 6) & 15, lane = s & 63;
    const int col = lane & 15, q = lane >> 4;
    float4 v = *(const float4*)(x + (mt * 16 + col) * IN_F + kt * 32 + q * 8 + half * 4);
    uint2 pv; pv.x = pack2(v.x, v.y); pv.y = pack2(v.z, v.w);
    *(uint2*)(xa + (size_t)s * 8 + half * 4) = pv;
}

// Fused: block (o, jhalf). Phase 1: m-strip [128][32] = x @ T[:, o*32..] via MFMA;
// B staged ONCE (K=512) in fragment-ordered LDS (conflict-free b128 reads);
// A-frags from global xa (L2). Only 3 barriers total. Phase 2: pairwise from mo.
__global__ __launch_bounds__(1024, 4) void fused_kernel(
    const unsigned short* __restrict__ xa,  // bf16 frags of x
    const float* __restrict__ T,            // fp32 [512][4096]
    float* __restrict__ out)                // fp32 [128][640]
{
    __shared__ unsigned short bs[2 * 16 * 64 * 8];  // 32 KB, frag-ordered B
    __shared__ float mo[B_SZ * MO_PITCH];           // 18 KB
    __shared__ float psum[2 * 32 * 33];             // 8.25 KB

    const int tid   = threadIdx.x;
    const int lane  = tid & 63;
    const int w     = tid >> 6;             // wave 0..15
    const int col   = lane & 15;
    const int q     = lane >> 4;
    const int o     = blockIdx.x >> 1;
    const int jhalf = blockIdx.x & 1;
    const int mt    = w >> 1, nt = w & 1;

    // ---- stage B: T[:, o*32..o*32+31] -> frag-ordered bs, whole K ----
    #pragma unroll
    for (int p = 0; p < 4; ++p) {
        int u  = tid + p * 1024;            // float4 unit, 0..4095
        int kk = u >> 3, cq = u & 7;
        float4 v = *(const float4*)(T + (size_t)kk * NC + o * 32 + cq * 4);
        int kt = kk >> 5, qq = (kk >> 3) & 3, j = kk & 7;
        float e[4] = {v.x, v.y, v.z, v.w};
        #pragma unroll
        for (int r = 0; r < 4; ++r) {
            int nn = cq * 4 + r;
            int ln = qq * 16 + (nn & 15);
            bs[((((nn >> 4) * 16 + kt) * 64) + ln) * 8 + j] = f2bfu(e[r]);
        }
    }
    __syncthreads();                        // barrier 1 (only K-loop barrier)

    // ---- MFMA loop: 16 x (global A-frag 1KB + LDS B-frag b128 + MFMA) ----
    f32x4 acc = {0.f, 0.f, 0.f, 0.f};
    const unsigned short* pa = xa + ((size_t)(mt * 16) * 64 + lane) * 8;
    const unsigned short* pb = bs + ((size_t)(nt * 16) * 64 + lane) * 8;
    #pragma unroll 4
    for (int kt = 0; kt < 16; ++kt) {
        bf16x8 af  = *(const bf16x8*)(pa + (size_t)kt * 512);
        bf16x8 bfr = *(const bf16x8*)(pb + (size_t)kt * 512);   // conflict-free b128
        acc = __builtin_amdgcn_mfma_f32_16x16x32_bf16(af, bfr, acc, 0, 0, 0);
    }
    // epilogue: C/D row = q*4+r, col = lane&15 (verified mapping)
    {
        float* dst = mo + (size_t)(mt * 16 + q * 4) * MO_PITCH + nt * 16 + col;
        dst[0 * MO_PITCH] = acc[0]; dst[1 * MO_PITCH] = acc[1];
        dst[2 * MO_PITCH] = acc[2]; dst[3 * MO_PITCH] = acc[3];
    }
    __syncthreads();                        // barrier 2

    // ---- Phase 2: o_b[j][o] = sum_i exp(-L1) - 1; 2 j per thread ----
    const int jj5 = tid & 31;
    const int isl = tid >> 5;               // 0..31, i-range = isl*4..+4
    const int j0  = jhalf * 64 + jj5;

    float mj0[KD], mj1[KD];
    #pragma unroll
    for (int k4 = 0; k4 < 8; ++k4) {
        float4 a = *(const float4*)(mo + (size_t)j0 * MO_PITCH + k4 * 4);
        float4 b = *(const float4*)(mo + (size_t)(j0 + 32) * MO_PITCH + k4 * 4);
        mj0[k4*4+0] = a.x; mj0[k4*4+1] = a.y; mj0[k4*4+2] = a.z; mj0[k4*4+3] = a.w;
        mj1[k4*4+0] = b.x; mj1[k4*4+1] = b.y; mj1[k4*4+2] = b.z; mj1[k4*4+3] = b.w;
    }

    float s0 = 0.f, s1 = 0.f;
    #pragma unroll
    for (int ii = 0; ii < 4; ++ii) {
        const int i = isl * 4 + ii;
        float n0 = 0.f, n1 = 0.f;
        #pragma unroll
        for (int k4 = 0; k4 < 8; ++k4) {
            float4 v = *(const float4*)(mo + (size_t)i * MO_PITCH + k4 * 4);
            n0 += fabsf(mj0[k4*4+0] - v.x) + fabsf(mj0[k4*4+1] - v.y)
                + fabsf(mj0[k4*4+2] - v.z) + fabsf(mj0[k4*4+3] - v.w);
            n1 += fabsf(mj1[k4*4+0] - v.x) + fabsf(mj1[k4*4+1] - v.y)
                + fabsf(mj1[k4*4+2] - v.z) + fabsf(mj1[k4*4+3] - v.w);
        }
        s0 += __expf(-n0);
        s1 += __expf(-n1);
    }
    psum[jj5 * 33 + isl]        = s0;       // pitch 33 -> conflict-free
    psum[1056 + jj5 * 33 + isl] = s1;
    __syncthreads();                        // barrier 3
    if (tid < 64) {
        int jsel = tid >> 5, jj = tid & 31;
        float tot = 0.f;
        #pragma unroll
        for (int u = 0; u < 32; ++u) tot += psum[jsel * 1056 + jj * 33 + u];
        out[(jhalf * 64 + jsel * 32 + jj) * OUT_COLS + IN_F + o] = tot - 1.0f;
    }
}

extern "C" void kernel_launch(void* const* d_in, const int* in_sizes, int n_in,
                              void* d_out, int out_size, void* d_ws, size_t ws_size,
                              hipStream_t stream) {
    const float* x = (const float*)d_in[0];
    const float* T = (const float*)d_in[1];
    float* out = (float*)d_out;
    unsigned short* xa = (unsigned short*)d_ws;     // 128 KB

    prep_kernel<<<64, 256, 0, stream>>>(x, out, xa);
    fused_kernel<<<256, 1024, 0, stream>>>(xa, T, out);
}